// Round 1
// baseline (181.239 us; speedup 1.0000x reference)
//
#include <hip/hip_runtime.h>

// ResGCNBlock: out = LN(relu(scatter_add(norm * (xW^T+b)[row] -> col))) + x
// N=50000, D=128, E=800000, fp32.
// Round 11 (polish): launch-merge + cache-residency pass.
//   - k_cast4 removed: GEMM blocks stage W fp32->bf16 into LDS in MFMA
//     fragment order (lane-contiguous ds_read_b128, conflict-free).
//   - k_scanp removed: k_rowptrc blocks redundantly scan the <=256 partials.
//   - __builtin_nontemporal_* on read-once/write-once streams (srcs, x
//     residual, out, ei/aux in k_fill, degc in k_partial) so L2 keeps the
//     hot reuse set (hb 12.8MB, dis, cntc, rowptrc) for the gather kernels.
//   History: global atomics dead on gfx950 (~26 G ops/s; r4 privatization
//   null, r7 scope demotion null) -> LDS histograms (r8); __shfl from
//   inactive lanes UNDEFINED -> wave-uniform trip counts in k_agg (r10).

#define D 128
#define CHSH 15                      // chunk = 32768 edges per hist block
#define CHUNK (1 << CHSH)
#define NWORD 12500                  // ceil(50000/4) packed-byte LDS words

typedef short bf16x8 __attribute__((ext_vector_type(8)));
typedef float f32x4 __attribute__((ext_vector_type(4)));

__device__ __forceinline__ unsigned short f2bf(float f) {
    unsigned u = __float_as_uint(f);
    return (unsigned short)((u + 0x7fffu + ((u >> 16) & 1u)) >> 16);
}
__device__ __forceinline__ float bf2f_lo(unsigned v) { return __uint_as_float(v << 16); }
__device__ __forceinline__ float bf2f_hi(unsigned v) { return __uint_as_float(v & 0xffff0000u); }

// ---------- merged (1024-thr): cnt-hist [0,K) + deg-hist [K,2K) + GEMM rest ----------
// GEMM blocks stage W (fp32 global) into LDS as bf16 in fragment order:
//   wf[((nt*4+kt)*64 + lane)*8 + j] = bf16(W[(nt*16+(lane&15))*D + kt*32 + (lane>>4)*8 + j])
// so the inner-loop B read is a lane-contiguous ds_read_b128 (conflict-free).
__global__ void __launch_bounds__(1024)
k_gemm_hist(const float* __restrict__ x, const float* __restrict__ W,
            const float* __restrict__ bias, unsigned short* __restrict__ hb,
            int nrows,
            const int* __restrict__ ei, int E, int n,
            unsigned char* __restrict__ degc, unsigned char* __restrict__ cntc,
            unsigned char* __restrict__ aux, int K) {
    __shared__ unsigned sm[NWORD];                 // 50 KB: hist OR W-frag staging
    int bid = blockIdx.x;
    if (bid < 2 * K) {
        unsigned* hist = sm;
        bool is_cnt = bid < K;
        int c = is_cnt ? bid : bid - K;
        const int* vs = is_cnt ? (ei + E) : ei;    // dest for cnt, source for deg
        for (int i = threadIdx.x; i < NWORD; i += 1024) hist[i] = 0u;
        __syncthreads();
        int e0 = c << CHSH;
        int e1 = e0 + CHUNK; if (e1 > E) e1 = E;
        if (is_cnt) {
            for (int e = e0 + threadIdx.x; e < e1; e += 1024) {
                int v = vs[e];
                unsigned sh = (v & 3) * 8;
                unsigned old = atomicAdd(&hist[v >> 2], 1u << sh);
                aux[e] = (unsigned char)(old >> sh);   // rank within (chunk, dest)
            }
        } else {
            for (int e = e0 + threadIdx.x; e < e1; e += 1024) {
                int v = vs[e];
                atomicAdd(&hist[v >> 2], 1u << ((v & 3) * 8));
            }
        }
        __syncthreads();
        unsigned* dst = (unsigned*)((is_cnt ? cntc : degc) + (size_t)c * n);
        for (int i = threadIdx.x; i < NWORD; i += 1024) dst[i] = hist[i];
    } else {
        // ---- GEMM role: 16 waves, 256 rows per block ----
        unsigned short* wf = (unsigned short*)sm;
        for (int s = threadIdx.x; s < D * D; s += 1024) {
            int j  = s & 7;
            int ln = (s >> 3) & 63;
            int g  = s >> 9;                       // nt*4 + kt
            int kt = g & 3, nt = g >> 2;
            int rw = nt * 16 + (ln & 15);
            int cl = kt * 32 + (ln >> 4) * 8 + j;
            wf[s] = f2bf(W[rw * D + cl]);
        }
        __syncthreads();

        int wid = threadIdx.x >> 6, lane = threadIdx.x & 63;
        int m0 = (bid - 2 * K) * 256 + wid * 16;
        if (m0 >= nrows) return;
        int lo16 = lane & 15, quad = lane >> 4;
        const float* arow = x + (size_t)(m0 + lo16) * D + quad * 8;
        bf16x8 a[4];
        #pragma unroll
        for (int kt = 0; kt < 4; kt++) {
            float4 p = *(const float4*)(arow + kt * 32);
            float4 q = *(const float4*)(arow + kt * 32 + 4);
            bf16x8 av;
            av[0] = (short)f2bf(p.x); av[1] = (short)f2bf(p.y);
            av[2] = (short)f2bf(p.z); av[3] = (short)f2bf(p.w);
            av[4] = (short)f2bf(q.x); av[5] = (short)f2bf(q.y);
            av[6] = (short)f2bf(q.z); av[7] = (short)f2bf(q.w);
            a[kt] = av;
        }
        const bf16x8* wfv = (const bf16x8*)wf;
        #pragma unroll
        for (int nt = 0; nt < 8; nt++) {
            int n0 = nt * 16;
            float bj = bias[n0 + lo16];
            f32x4 acc = {bj, bj, bj, bj};
            #pragma unroll
            for (int kt = 0; kt < 4; kt++) {
                bf16x8 b = wfv[(nt * 4 + kt) * 64 + lane];
                acc = __builtin_amdgcn_mfma_f32_16x16x32_bf16(a[kt], b, acc, 0, 0, 0);
            }
            #pragma unroll
            for (int r = 0; r < 4; r++) {
                int gr = m0 + quad * 4 + r;
                hb[(size_t)gr * D + n0 + lo16] = f2bf(acc[r]);
            }
        }
    }
}

// ---------- reduce byte-copies (dis, cnt) + per-block partial sums of cnt ----------
__global__ void k_partial(const unsigned char* __restrict__ degc,
                          const unsigned char* __restrict__ cntc,
                          float* __restrict__ dis, unsigned* __restrict__ cnt,
                          unsigned* __restrict__ partial, int n, int K) {
    __shared__ unsigned s[256];
    int t = threadIdx.x;
    int i = blockIdx.x * 256 + t;
    unsigned tot = 0;
    if (i < n) {
        unsigned d = 0;
        for (int c = 0; c < K; c++)
            d += __builtin_nontemporal_load(degc + (size_t)c * n + i);  // read-once
        dis[i] = rsqrtf((float)d + 1.0f);          // +1 = self loop
        for (int c = 0; c < K; c++) tot += cntc[(size_t)c * n + i];     // re-read in rowptrc: keep cached
        cnt[i] = tot;
    }
    s[t] = tot;
    __syncthreads();
    #pragma unroll
    for (int d = 128; d > 0; d >>= 1) {
        if (t < d) s[t] += s[t + d];
        __syncthreads();
    }
    if (t == 0) partial[blockIdx.x] = s[0];
}

// ---------- rowptr + per-copy rowptr; partials scanned redundantly per block ----------
__global__ void k_rowptrc(const unsigned* __restrict__ cnt, const unsigned char* __restrict__ cntc,
                          const unsigned* __restrict__ partial, int n, int E,
                          int* __restrict__ rowptr, int* __restrict__ rowptrc, int K, int nb) {
    __shared__ unsigned ps[256];
    __shared__ unsigned base_sh;
    int t = threadIdx.x;
    // inline exclusive scan of block partials (nb <= 256): replaces k_scanp
    unsigned pv = (t < nb) ? partial[t] : 0u;
    ps[t] = pv;
    __syncthreads();
    #pragma unroll
    for (int d = 1; d < 256; d <<= 1) {
        unsigned u = (t >= d) ? ps[t - d] : 0u;
        __syncthreads();
        ps[t] += u;
        __syncthreads();
    }
    if (t == blockIdx.x) base_sh = ps[t] - pv;     // exclusive prefix for this block
    __syncthreads();
    unsigned bbase = base_sh;
    // per-node scan within block
    int i = blockIdx.x * 256 + t;
    unsigned v = (i < n) ? cnt[i] : 0u;
    ps[t] = v;
    __syncthreads();
    #pragma unroll
    for (int d = 1; d < 256; d <<= 1) {
        unsigned u = (t >= d) ? ps[t - d] : 0u;
        __syncthreads();
        ps[t] += u;
        __syncthreads();
    }
    if (i < n) {
        int base = (int)(bbase + ps[t] - v);
        rowptr[i] = base;
        unsigned run = 0;
        for (int c = 0; c < K; c++) {
            rowptrc[(size_t)c * n + i] = base + (int)run;
            run += cntc[(size_t)c * n + i];
        }
    }
    if (blockIdx.x == 0 && t == 0) rowptr[n] = E;
}

// ---------- atomic-free bucket fill using (copy = e>>CHSH, rank = aux[e]) ----------
__global__ void k_fill(const int* __restrict__ ei, int E, int n,
                       const int* __restrict__ rowptrc, const unsigned char* __restrict__ aux,
                       int* __restrict__ srcs) {
    int e = blockIdx.x * 256 + threadIdx.x;
    if (e < E) {
        int r = __builtin_nontemporal_load(ei + e);          // read-once
        int v = __builtin_nontemporal_load(ei + E + e);      // read-once
        int c = e >> CHSH;
        int rank = __builtin_nontemporal_load(aux + e);      // read-once
        srcs[rowptrc[(size_t)c * n + v] + rank] = r;         // rowptrc: line-reused, keep cached
    }
}

// ---------- fused gather-aggregate + self-loop + relu + LN + residual ----------
// one wave per dest row; quad q (16 lanes) handles edges j==q (mod 4); lane t
// owns cols 8t..8t+7 (16B uint4 of bf16 per edge). Uniform trip count; all
// shuffles full-wave (ds_bpermute from inactive lanes is UNDEFINED on gfx950).
__global__ void k_agg(const float* __restrict__ x, const unsigned short* __restrict__ hb,
                      const float* __restrict__ dis,
                      const int* __restrict__ rowptr, const int* __restrict__ srcs,
                      const float* __restrict__ gamma, const float* __restrict__ beta,
                      float* __restrict__ out, int n) {
    int wid = threadIdx.x >> 6, lane = threadIdx.x & 63;
    int row = blockIdx.x * 4 + wid;
    if (row >= n) return;
    int q = lane >> 4, t = lane & 15;
    float dc = dis[row];
    float acc[8];
    #pragma unroll
    for (int i = 0; i < 8; i++) acc[i] = 0.0f;
    if (q == 0) {                                     // self-loop: dis^2 * h[row]
        uint4 u = ((const uint4*)(hb + (size_t)row * D))[t];
        float sn = dc * dc;
        acc[0] = sn * bf2f_lo(u.x); acc[1] = sn * bf2f_hi(u.x);
        acc[2] = sn * bf2f_lo(u.y); acc[3] = sn * bf2f_hi(u.y);
        acc[4] = sn * bf2f_lo(u.z); acc[5] = sn * bf2f_hi(u.z);
        acc[6] = sn * bf2f_lo(u.w); acc[7] = sn * bf2f_hi(u.w);
    }
    int s0 = rowptr[row];
    int len = rowptr[row + 1] - s0;
    for (int base = 0; base < len; base += 64) {
        int idx = base + lane;
        int sv = (idx < len) ? __builtin_nontemporal_load(srcs + s0 + idx) : 0;  // read-once stream
        float dv = (idx < len) ? dis[sv] : 0.0f;      // pad: weight 0 (self-masks)
        int m = len - base; if (m > 64) m = 64;
        int kmax = (m + 3) >> 2;                      // wave-uniform trip count
        int j = q;
        int r = __shfl(sv, j, 64);                    // full-wave shuffle: defined
        float nm = dc * __shfl(dv, j, 64);            // 0 if j >= m
        uint4 u = ((const uint4*)(hb + (size_t)r * D))[t];
        for (int k = 1; k < kmax; k++) {
            int jn = j + 4;                           // jn <= 63 (kmax <= 16)
            int rn = __shfl(sv, jn, 64);              // prefetch next edge
            float nmn = dc * __shfl(dv, jn, 64);
            uint4 un = ((const uint4*)(hb + (size_t)rn * D))[t];
            acc[0] += nm * bf2f_lo(u.x); acc[1] += nm * bf2f_hi(u.x);
            acc[2] += nm * bf2f_lo(u.y); acc[3] += nm * bf2f_hi(u.y);
            acc[4] += nm * bf2f_lo(u.z); acc[5] += nm * bf2f_hi(u.z);
            acc[6] += nm * bf2f_lo(u.w); acc[7] += nm * bf2f_hi(u.w);
            u = un; nm = nmn; j = jn;
        }
        acc[0] += nm * bf2f_lo(u.x); acc[1] += nm * bf2f_hi(u.x);
        acc[2] += nm * bf2f_lo(u.y); acc[3] += nm * bf2f_hi(u.y);
        acc[4] += nm * bf2f_lo(u.z); acc[5] += nm * bf2f_hi(u.z);
        acc[6] += nm * bf2f_lo(u.w); acc[7] += nm * bf2f_hi(u.w);
    }
    // combine the 4 quads' partials (lanes t, t+16, t+32, t+48), then relu
    #pragma unroll
    for (int i = 0; i < 8; i++) {
        acc[i] += __shfl_xor(acc[i], 16, 64);
        acc[i] += __shfl_xor(acc[i], 32, 64);
        acc[i] = acc[i] > 0.0f ? acc[i] : 0.0f;
    }
    // LN over 128 cols: per-lane partial over its 8 cols, reduce across t
    float s1r = 0.0f, s2r = 0.0f;
    #pragma unroll
    for (int i = 0; i < 8; i++) { s1r += acc[i]; s2r += acc[i] * acc[i]; }
    #pragma unroll
    for (int mm = 8; mm >= 1; mm >>= 1) {
        s1r += __shfl_xor(s1r, mm, 64);
        s2r += __shfl_xor(s2r, mm, 64);
    }
    float mean = s1r * (1.0f / 128.0f);
    float var  = s2r * (1.0f / 128.0f) - mean * mean;  // population var (jnp.var)
    float rstd = rsqrtf(var + 1e-5f);
    if (q == 0) {                                      // 16 lanes store the row
        const f32x4* gr = (const f32x4*)gamma;
        const f32x4* br = (const f32x4*)beta;
        const f32x4* xr = (const f32x4*)(x + (size_t)row * D);
        f32x4* orow = (f32x4*)(out + (size_t)row * D);
        #pragma unroll
        for (int hf = 0; hf < 2; hf++) {
            f32x4 g = gr[2 * t + hf], b = br[2 * t + hf];
            f32x4 xx = __builtin_nontemporal_load(xr + 2 * t + hf);   // read-once
            f32x4 o;
            o[0] = (acc[4 * hf + 0] - mean) * rstd * g[0] + b[0] + xx[0];
            o[1] = (acc[4 * hf + 1] - mean) * rstd * g[1] + b[1] + xx[1];
            o[2] = (acc[4 * hf + 2] - mean) * rstd * g[2] + b[2] + xx[2];
            o[3] = (acc[4 * hf + 3] - mean) * rstd * g[3] + b[3] + xx[3];
            __builtin_nontemporal_store(o, orow + 2 * t + hf);        // write-once
        }
    }
}

extern "C" void kernel_launch(void* const* d_in, const int* in_sizes, int n_in,
                              void* d_out, int out_size, void* d_ws, size_t ws_size,
                              hipStream_t stream) {
    const float* x     = (const float*)d_in[0];
    const int*   ei    = (const int*)d_in[1];   // [2, E]
    const float* W     = (const float*)d_in[2];
    const float* bias  = (const float*)d_in[3];
    const float* gamma = (const float*)d_in[4];
    const float* beta  = (const float*)d_in[5];
    int N = in_sizes[0] / D;
    int E = in_sizes[1] / 2;
    int nb  = (N + 255) / 256;                   // 196 scan blocks (<=256)
    int nbE = (E + 255) / 256;                   // 3125
    int K   = (E + CHUNK - 1) >> CHSH;           // 25 chunks / copies
    int gemm_blocks = (N + 255) / 256;           // 196 (256 rows per 1024-thr block)

    char* ws = (char*)d_ws;
    size_t off = 0;
    unsigned short* hb  = (unsigned short*)(ws + off); off += (size_t)N * D * 2;       // 12.8 MB
    unsigned char* degc = (unsigned char*)(ws + off);  off += (size_t)K * N;           // 1.25 MB
    unsigned char* cntc = (unsigned char*)(ws + off);  off += (size_t)K * N;           // 1.25 MB
    float*    dis       = (float*)(ws + off);          off += (size_t)N * 4;
    unsigned* cnt       = (unsigned*)(ws + off);       off += (size_t)N * 4;
    int*      rowptr    = (int*)(ws + off);            off += (size_t)(N + 1) * 4;
    int*      rowptrc   = (int*)(ws + off);            off += (size_t)K * N * 4;       // 5 MB
    unsigned* partial   = (unsigned*)(ws + off);       off += 256 * 4;
    unsigned char* aux  = (unsigned char*)(ws + off);  off += (size_t)E;               // 0.8 MB
    int*      srcs      = (int*)(ws + off);            off += (size_t)E * 4;           // 3.2 MB
    float*    out       = (float*)d_out;

    k_gemm_hist<<<2 * K + gemm_blocks, 1024, 0, stream>>>(x, W, bias, hb, N,
                                                          ei, E, N, degc, cntc, aux, K);
    k_partial<<<nb, 256, 0, stream>>>(degc, cntc, dis, cnt, partial, N, K);
    k_rowptrc<<<nb, 256, 0, stream>>>(cnt, cntc, partial, N, E, rowptr, rowptrc, K, nb);
    k_fill<<<nbE, 256, 0, stream>>>(ei, E, N, rowptrc, aux, srcs);
    k_agg<<<(N + 3) / 4, 256, 0, stream>>>(x, hb, dis, rowptr, srcs, gamma, beta, out, N);
}

// Round 2
// 177.635 us; speedup vs baseline: 1.0203x; 1.0203x over previous
//
#include <hip/hip_runtime.h>

// ResGCNBlock: out = LN(relu(scatter_add(norm * (xW^T+b)[row] -> col))) + x
// N=50000, D=128, E=800000, fp32.
// Round 12: k_agg deep-MLP restructure. rocprof r11: k_agg = 44.3us,
//   hbm 34% peak, VALU 47%, Mfma 0 -> latency-bound gather (only 2 loads in
//   flight per lane, avg row = 16 edges = 4 serial rounds/quad). Fix: 4-wide
//   load groups -- issue 4 independent uint4 gathers per quad before
//   consuming (wave-uniform group count; shuffles stay full-wave, pad lanes
//   sv=0/dv=0 self-mask; extra stages in last group load row 0 @ weight 0).
//   History: global atomics dead on gfx950 (~26 G ops/s; r4 privatization
//   null, r7 scope demotion null) -> LDS histograms (r8); __shfl from
//   inactive lanes UNDEFINED -> wave-uniform trip counts (r10); launch-merge
//   + nontemporal streams (r11, neutral).

#define D 128
#define CHSH 15                      // chunk = 32768 edges per hist block
#define CHUNK (1 << CHSH)
#define NWORD 12500                  // ceil(50000/4) packed-byte LDS words

typedef short bf16x8 __attribute__((ext_vector_type(8)));
typedef float f32x4 __attribute__((ext_vector_type(4)));

__device__ __forceinline__ unsigned short f2bf(float f) {
    unsigned u = __float_as_uint(f);
    return (unsigned short)((u + 0x7fffu + ((u >> 16) & 1u)) >> 16);
}
__device__ __forceinline__ float bf2f_lo(unsigned v) { return __uint_as_float(v << 16); }
__device__ __forceinline__ float bf2f_hi(unsigned v) { return __uint_as_float(v & 0xffff0000u); }

// ---------- merged (1024-thr): cnt-hist [0,K) + deg-hist [K,2K) + GEMM rest ----------
__global__ void __launch_bounds__(1024)
k_gemm_hist(const float* __restrict__ x, const float* __restrict__ W,
            const float* __restrict__ bias, unsigned short* __restrict__ hb,
            int nrows,
            const int* __restrict__ ei, int E, int n,
            unsigned char* __restrict__ degc, unsigned char* __restrict__ cntc,
            unsigned char* __restrict__ aux, int K) {
    __shared__ unsigned sm[NWORD];                 // 50 KB: hist OR W-frag staging
    int bid = blockIdx.x;
    if (bid < 2 * K) {
        unsigned* hist = sm;
        bool is_cnt = bid < K;
        int c = is_cnt ? bid : bid - K;
        const int* vs = is_cnt ? (ei + E) : ei;    // dest for cnt, source for deg
        for (int i = threadIdx.x; i < NWORD; i += 1024) hist[i] = 0u;
        __syncthreads();
        int e0 = c << CHSH;
        int e1 = e0 + CHUNK; if (e1 > E) e1 = E;
        if (is_cnt) {
            for (int e = e0 + threadIdx.x; e < e1; e += 1024) {
                int v = vs[e];
                unsigned sh = (v & 3) * 8;
                unsigned old = atomicAdd(&hist[v >> 2], 1u << sh);
                aux[e] = (unsigned char)(old >> sh);   // rank within (chunk, dest)
            }
        } else {
            for (int e = e0 + threadIdx.x; e < e1; e += 1024) {
                int v = vs[e];
                atomicAdd(&hist[v >> 2], 1u << ((v & 3) * 8));
            }
        }
        __syncthreads();
        unsigned* dst = (unsigned*)((is_cnt ? cntc : degc) + (size_t)c * n);
        for (int i = threadIdx.x; i < NWORD; i += 1024) dst[i] = hist[i];
    } else {
        // ---- GEMM role: 16 waves, 256 rows per block ----
        unsigned short* wf = (unsigned short*)sm;
        for (int s = threadIdx.x; s < D * D; s += 1024) {
            int j  = s & 7;
            int ln = (s >> 3) & 63;
            int g  = s >> 9;                       // nt*4 + kt
            int kt = g & 3, nt = g >> 2;
            int rw = nt * 16 + (ln & 15);
            int cl = kt * 32 + (ln >> 4) * 8 + j;
            wf[s] = f2bf(W[rw * D + cl]);
        }
        __syncthreads();

        int wid = threadIdx.x >> 6, lane = threadIdx.x & 63;
        int m0 = (bid - 2 * K) * 256 + wid * 16;
        if (m0 >= nrows) return;
        int lo16 = lane & 15, quad = lane >> 4;
        const float* arow = x + (size_t)(m0 + lo16) * D + quad * 8;
        bf16x8 a[4];
        #pragma unroll
        for (int kt = 0; kt < 4; kt++) {
            float4 p = *(const float4*)(arow + kt * 32);
            float4 q = *(const float4*)(arow + kt * 32 + 4);
            bf16x8 av;
            av[0] = (short)f2bf(p.x); av[1] = (short)f2bf(p.y);
            av[2] = (short)f2bf(p.z); av[3] = (short)f2bf(p.w);
            av[4] = (short)f2bf(q.x); av[5] = (short)f2bf(q.y);
            av[6] = (short)f2bf(q.z); av[7] = (short)f2bf(q.w);
            a[kt] = av;
        }
        const bf16x8* wfv = (const bf16x8*)wf;
        #pragma unroll
        for (int nt = 0; nt < 8; nt++) {
            int n0 = nt * 16;
            float bj = bias[n0 + lo16];
            f32x4 acc = {bj, bj, bj, bj};
            #pragma unroll
            for (int kt = 0; kt < 4; kt++) {
                bf16x8 b = wfv[(nt * 4 + kt) * 64 + lane];
                acc = __builtin_amdgcn_mfma_f32_16x16x32_bf16(a[kt], b, acc, 0, 0, 0);
            }
            #pragma unroll
            for (int r = 0; r < 4; r++) {
                int gr = m0 + quad * 4 + r;
                hb[(size_t)gr * D + n0 + lo16] = f2bf(acc[r]);
            }
        }
    }
}

// ---------- reduce byte-copies (dis, cnt) + per-block partial sums of cnt ----------
__global__ void k_partial(const unsigned char* __restrict__ degc,
                          const unsigned char* __restrict__ cntc,
                          float* __restrict__ dis, unsigned* __restrict__ cnt,
                          unsigned* __restrict__ partial, int n, int K) {
    __shared__ unsigned s[256];
    int t = threadIdx.x;
    int i = blockIdx.x * 256 + t;
    unsigned tot = 0;
    if (i < n) {
        unsigned d = 0;
        for (int c = 0; c < K; c++)
            d += __builtin_nontemporal_load(degc + (size_t)c * n + i);  // read-once
        dis[i] = rsqrtf((float)d + 1.0f);          // +1 = self loop
        for (int c = 0; c < K; c++) tot += cntc[(size_t)c * n + i];     // re-read in rowptrc
        cnt[i] = tot;
    }
    s[t] = tot;
    __syncthreads();
    #pragma unroll
    for (int d = 128; d > 0; d >>= 1) {
        if (t < d) s[t] += s[t + d];
        __syncthreads();
    }
    if (t == 0) partial[blockIdx.x] = s[0];
}

// ---------- rowptr + per-copy rowptr; partials scanned redundantly per block ----------
__global__ void k_rowptrc(const unsigned* __restrict__ cnt, const unsigned char* __restrict__ cntc,
                          const unsigned* __restrict__ partial, int n, int E,
                          int* __restrict__ rowptr, int* __restrict__ rowptrc, int K, int nb) {
    __shared__ unsigned ps[256];
    __shared__ unsigned base_sh;
    int t = threadIdx.x;
    // inline exclusive scan of block partials (nb <= 256): replaces k_scanp
    unsigned pv = (t < nb) ? partial[t] : 0u;
    ps[t] = pv;
    __syncthreads();
    #pragma unroll
    for (int d = 1; d < 256; d <<= 1) {
        unsigned u = (t >= d) ? ps[t - d] : 0u;
        __syncthreads();
        ps[t] += u;
        __syncthreads();
    }
    if (t == blockIdx.x) base_sh = ps[t] - pv;     // exclusive prefix for this block
    __syncthreads();
    unsigned bbase = base_sh;
    // per-node scan within block
    int i = blockIdx.x * 256 + t;
    unsigned v = (i < n) ? cnt[i] : 0u;
    ps[t] = v;
    __syncthreads();
    #pragma unroll
    for (int d = 1; d < 256; d <<= 1) {
        unsigned u = (t >= d) ? ps[t - d] : 0u;
        __syncthreads();
        ps[t] += u;
        __syncthreads();
    }
    if (i < n) {
        int base = (int)(bbase + ps[t] - v);
        rowptr[i] = base;
        unsigned run = 0;
        for (int c = 0; c < K; c++) {
            rowptrc[(size_t)c * n + i] = base + (int)run;
            run += cntc[(size_t)c * n + i];
        }
    }
    if (blockIdx.x == 0 && t == 0) rowptr[n] = E;
}

// ---------- atomic-free bucket fill using (copy = e>>CHSH, rank = aux[e]) ----------
__global__ void k_fill(const int* __restrict__ ei, int E, int n,
                       const int* __restrict__ rowptrc, const unsigned char* __restrict__ aux,
                       int* __restrict__ srcs) {
    int e = blockIdx.x * 256 + threadIdx.x;
    if (e < E) {
        int r = __builtin_nontemporal_load(ei + e);          // read-once
        int v = __builtin_nontemporal_load(ei + E + e);      // read-once
        int c = e >> CHSH;
        int rank = __builtin_nontemporal_load(aux + e);      // read-once
        srcs[rowptrc[(size_t)c * n + v] + rank] = r;         // rowptrc: line-reused
    }
}

// ---------- fused gather-aggregate + self-loop + relu + LN + residual ----------
// one wave per dest row; quad q (16 lanes) handles edges j==q (mod 4); lane t
// owns cols 8t..8t+7 (16B uint4 of bf16 per edge). 4-wide load groups: issue
// 4 independent gathers per quad, then consume (r12). Group count is
// wave-uniform; all shuffles full-wave (inactive-lane shuffle UNDEFINED).
__global__ void k_agg(const float* __restrict__ x, const unsigned short* __restrict__ hb,
                      const float* __restrict__ dis,
                      const int* __restrict__ rowptr, const int* __restrict__ srcs,
                      const float* __restrict__ gamma, const float* __restrict__ beta,
                      float* __restrict__ out, int n) {
    int wid = threadIdx.x >> 6, lane = threadIdx.x & 63;
    int row = blockIdx.x * 4 + wid;
    if (row >= n) return;
    int q = lane >> 4, t = lane & 15;
    float dc = dis[row];
    float acc[8];
    #pragma unroll
    for (int i = 0; i < 8; i++) acc[i] = 0.0f;
    if (q == 0) {                                     // self-loop: dis^2 * h[row]
        uint4 u = ((const uint4*)(hb + (size_t)row * D))[t];
        float sn = dc * dc;
        acc[0] = sn * bf2f_lo(u.x); acc[1] = sn * bf2f_hi(u.x);
        acc[2] = sn * bf2f_lo(u.y); acc[3] = sn * bf2f_hi(u.y);
        acc[4] = sn * bf2f_lo(u.z); acc[5] = sn * bf2f_hi(u.z);
        acc[6] = sn * bf2f_lo(u.w); acc[7] = sn * bf2f_hi(u.w);
    }
    int s0 = rowptr[row];
    int len = rowptr[row + 1] - s0;
    for (int base = 0; base < len; base += 64) {
        int idx = base + lane;
        int sv = (idx < len) ? __builtin_nontemporal_load(srcs + s0 + idx) : 0;
        float dv = (idx < len) ? dis[sv] : 0.0f;      // pad: weight 0 (self-masks)
        int m = len - base; if (m > 64) m = 64;
        int kmax = (m + 3) >> 2;                      // 1..16, wave-uniform
        int gcount = (kmax + 3) >> 2;                 // 1..4 groups of 4 edges/quad
        for (int gg = 0; gg < gcount; gg++) {         // wave-uniform trip count
            int jb = q + (gg << 4);                   // jb+12 <= 63
            // full-wave shuffles for the whole group up front
            int r0 = __shfl(sv, jb, 64);
            int r1 = __shfl(sv, jb + 4, 64);
            int r2 = __shfl(sv, jb + 8, 64);
            int r3 = __shfl(sv, jb + 12, 64);
            float w0 = dc * __shfl(dv, jb, 64);       // 0 for stages >= m
            float w1 = dc * __shfl(dv, jb + 4, 64);
            float w2 = dc * __shfl(dv, jb + 8, 64);
            float w3 = dc * __shfl(dv, jb + 12, 64);
            // 4 independent gathers in flight before any consume
            uint4 u0 = ((const uint4*)(hb + ((size_t)r0 << 7)))[t];
            uint4 u1 = ((const uint4*)(hb + ((size_t)r1 << 7)))[t];
            uint4 u2 = ((const uint4*)(hb + ((size_t)r2 << 7)))[t];
            uint4 u3 = ((const uint4*)(hb + ((size_t)r3 << 7)))[t];
            acc[0] += w0 * bf2f_lo(u0.x); acc[1] += w0 * bf2f_hi(u0.x);
            acc[2] += w0 * bf2f_lo(u0.y); acc[3] += w0 * bf2f_hi(u0.y);
            acc[4] += w0 * bf2f_lo(u0.z); acc[5] += w0 * bf2f_hi(u0.z);
            acc[6] += w0 * bf2f_lo(u0.w); acc[7] += w0 * bf2f_hi(u0.w);
            acc[0] += w1 * bf2f_lo(u1.x); acc[1] += w1 * bf2f_hi(u1.x);
            acc[2] += w1 * bf2f_lo(u1.y); acc[3] += w1 * bf2f_hi(u1.y);
            acc[4] += w1 * bf2f_lo(u1.z); acc[5] += w1 * bf2f_hi(u1.z);
            acc[6] += w1 * bf2f_lo(u1.w); acc[7] += w1 * bf2f_hi(u1.w);
            acc[0] += w2 * bf2f_lo(u2.x); acc[1] += w2 * bf2f_hi(u2.x);
            acc[2] += w2 * bf2f_lo(u2.y); acc[3] += w2 * bf2f_hi(u2.y);
            acc[4] += w2 * bf2f_lo(u2.z); acc[5] += w2 * bf2f_hi(u2.z);
            acc[6] += w2 * bf2f_lo(u2.w); acc[7] += w2 * bf2f_hi(u2.w);
            acc[0] += w3 * bf2f_lo(u3.x); acc[1] += w3 * bf2f_hi(u3.x);
            acc[2] += w3 * bf2f_lo(u3.y); acc[3] += w3 * bf2f_hi(u3.y);
            acc[4] += w3 * bf2f_lo(u3.z); acc[5] += w3 * bf2f_hi(u3.z);
            acc[6] += w3 * bf2f_lo(u3.w); acc[7] += w3 * bf2f_hi(u3.w);
        }
    }
    // combine the 4 quads' partials (lanes t, t+16, t+32, t+48), then relu
    #pragma unroll
    for (int i = 0; i < 8; i++) {
        acc[i] += __shfl_xor(acc[i], 16, 64);
        acc[i] += __shfl_xor(acc[i], 32, 64);
        acc[i] = acc[i] > 0.0f ? acc[i] : 0.0f;
    }
    // LN over 128 cols: per-lane partial over its 8 cols, reduce across t
    float s1r = 0.0f, s2r = 0.0f;
    #pragma unroll
    for (int i = 0; i < 8; i++) { s1r += acc[i]; s2r += acc[i] * acc[i]; }
    #pragma unroll
    for (int mm = 8; mm >= 1; mm >>= 1) {
        s1r += __shfl_xor(s1r, mm, 64);
        s2r += __shfl_xor(s2r, mm, 64);
    }
    float mean = s1r * (1.0f / 128.0f);
    float var  = s2r * (1.0f / 128.0f) - mean * mean;  // population var (jnp.var)
    float rstd = rsqrtf(var + 1e-5f);
    if (q == 0) {                                      // 16 lanes store the row
        const f32x4* gr = (const f32x4*)gamma;
        const f32x4* br = (const f32x4*)beta;
        const f32x4* xr = (const f32x4*)(x + (size_t)row * D);
        f32x4* orow = (f32x4*)(out + (size_t)row * D);
        #pragma unroll
        for (int hf = 0; hf < 2; hf++) {
            f32x4 g = gr[2 * t + hf], b = br[2 * t + hf];
            f32x4 xx = __builtin_nontemporal_load(xr + 2 * t + hf);   // read-once
            f32x4 o;
            o[0] = (acc[4 * hf + 0] - mean) * rstd * g[0] + b[0] + xx[0];
            o[1] = (acc[4 * hf + 1] - mean) * rstd * g[1] + b[1] + xx[1];
            o[2] = (acc[4 * hf + 2] - mean) * rstd * g[2] + b[2] + xx[2];
            o[3] = (acc[4 * hf + 3] - mean) * rstd * g[3] + b[3] + xx[3];
            __builtin_nontemporal_store(o, orow + 2 * t + hf);        // write-once
        }
    }
}

extern "C" void kernel_launch(void* const* d_in, const int* in_sizes, int n_in,
                              void* d_out, int out_size, void* d_ws, size_t ws_size,
                              hipStream_t stream) {
    const float* x     = (const float*)d_in[0];
    const int*   ei    = (const int*)d_in[1];   // [2, E]
    const float* W     = (const float*)d_in[2];
    const float* bias  = (const float*)d_in[3];
    const float* gamma = (const float*)d_in[4];
    const float* beta  = (const float*)d_in[5];
    int N = in_sizes[0] / D;
    int E = in_sizes[1] / 2;
    int nb  = (N + 255) / 256;                   // 196 scan blocks (<=256)
    int nbE = (E + 255) / 256;                   // 3125
    int K   = (E + CHUNK - 1) >> CHSH;           // 25 chunks / copies
    int gemm_blocks = (N + 255) / 256;           // 196 (256 rows per 1024-thr block)

    char* ws = (char*)d_ws;
    size_t off = 0;
    unsigned short* hb  = (unsigned short*)(ws + off); off += (size_t)N * D * 2;       // 12.8 MB
    unsigned char* degc = (unsigned char*)(ws + off);  off += (size_t)K * N;           // 1.25 MB
    unsigned char* cntc = (unsigned char*)(ws + off);  off += (size_t)K * N;           // 1.25 MB
    float*    dis       = (float*)(ws + off);          off += (size_t)N * 4;
    unsigned* cnt       = (unsigned*)(ws + off);       off += (size_t)N * 4;
    int*      rowptr    = (int*)(ws + off);            off += (size_t)(N + 1) * 4;
    int*      rowptrc   = (int*)(ws + off);            off += (size_t)K * N * 4;       // 5 MB
    unsigned* partial   = (unsigned*)(ws + off);       off += 256 * 4;
    unsigned char* aux  = (unsigned char*)(ws + off);  off += (size_t)E;               // 0.8 MB
    int*      srcs      = (int*)(ws + off);            off += (size_t)E * 4;           // 3.2 MB
    float*    out       = (float*)d_out;

    k_gemm_hist<<<2 * K + gemm_blocks, 1024, 0, stream>>>(x, W, bias, hb, N,
                                                          ei, E, N, degc, cntc, aux, K);
    k_partial<<<nb, 256, 0, stream>>>(degc, cntc, dis, cnt, partial, N, K);
    k_rowptrc<<<nb, 256, 0, stream>>>(cnt, cntc, partial, N, E, rowptr, rowptrc, K, nb);
    k_fill<<<nbE, 256, 0, stream>>>(ei, E, N, rowptrc, aux, srcs);
    k_agg<<<(N + 3) / 4, 256, 0, stream>>>(x, hb, dis, rowptr, srcs, gamma, beta, out, N);
}